// Round 1
// 774.904 us; speedup vs baseline: 1.1344x; 1.1344x over previous
//
#include <hip/hip_runtime.h>
#include <hip/hip_bf16.h>

#define VV 30000
#define HH 128
#define SS 32
#define UU 128
#define EE 300000

typedef unsigned short u16;
typedef unsigned int u32;

__device__ __forceinline__ u16 f2b(float f){ union{float f; u32 i;} v; v.f=f; u32 x=v.i; x += 0x7fffu + ((x>>16)&1u); return (u16)(x>>16); }

typedef __bf16 bf16x8 __attribute__((ext_vector_type(8)));
typedef float f32x4 __attribute__((ext_vector_type(4)));

__device__ __forceinline__ void gl_lds16(const void* g, void* l){
  __builtin_amdgcn_global_load_lds((const __attribute__((address_space(1))) u32*)g,
                                   (__attribute__((address_space(3))) u32*)l, 16, 0, 0);
}

// ---------------- graph conv ----------------
// merged flag (x -> needed) + degree (rows -> deg). grid = 1172 blocks covers EE.
__global__ __launch_bounds__(256) void k_flagdeg(const int* __restrict__ x, const int* __restrict__ rows,
    int* __restrict__ needed, int* __restrict__ deg){
  int gid = blockIdx.x*256 + threadIdx.x;
  if (gid < SS*UU) needed[x[gid]] = 1;
  if (gid < EE) atomicAdd(&deg[rows[gid]], 1);
}

// grid-stride over edges: 2048 blocks, 2 edges per block-iteration (128 threads/edge).
__global__ __launch_bounds__(256) void k_agg(const int* __restrict__ rows, const int* __restrict__ cols,
    const float* __restrict__ enc, const int* __restrict__ needed, float* __restrict__ agg){
  int hh  = threadIdx.x & 127;
  int sub = threadIdx.x >> 7;
  int stride = gridDim.x * 2;
  for (int e = blockIdx.x*2 + sub; e < EE; e += stride){
    int r = rows[e];                 // wave-uniform -> scalar load
    if (!needed[r]) continue;        // wave-uniform branch
    int c = cols[e];
    atomicAdd(&agg[(size_t)r*HH + hh], enc[(size_t)c*HH + hh]);
  }
}

__global__ __launch_bounds__(128) void k_xemb(const int* __restrict__ x, const float* __restrict__ agg,
    const float* __restrict__ enc, const int* __restrict__ deg, float* __restrict__ xemb){
  int su = blockIdx.x, hh = threadIdx.x;
  int v = x[su];
  float d = (float)(deg[v] + 1);
  xemb[su*HH + hh] = (agg[(size_t)v*HH + hh] + enc[(size_t)v*HH + hh]) / d;
}

// ---------------- RNN: one block per user, weights in registers ----------------
__global__ __launch_bounds__(256) void k_rnn(const float* __restrict__ xemb,
     const float* __restrict__ h0, const float* __restrict__ Wih, const float* __restrict__ Whh,
     const float* __restrict__ brnn, float* __restrict__ outws, float* __restrict__ hlast)
{
  int u = blockIdx.x, t = threadIdx.x;
  int d = t & 127, half = t >> 7;
  __shared__ float xbuf[128], hbuf[128], part[256];
  float wf[128];
  const float4* wr4 = (const float4*)((half ? Whh : Wih) + d*HH);
  #pragma unroll
  for(int i=0;i<32;i++){
    float4 q = wr4[i];
    wf[4*i+0]=q.x; wf[4*i+1]=q.y; wf[4*i+2]=q.z; wf[4*i+3]=q.w;
  }
  float bias = 0.f;
  if (t < 128){ hbuf[t] = h0[u*HH + t]; bias = brnn[t]; }
  for(int s0=0; s0<SS; ++s0){
    if (t < 128) xbuf[t] = xemb[(s0*UU + u)*HH + t];
    __syncthreads();
    const float4* vp = (const float4*)(half ? hbuf : xbuf);
    // 4 independent accumulators break the dependent-FMA chain
    float a0=0.f, a1=0.f, a2=0.f, a3=0.f;
    #pragma unroll
    for(int k4=0;k4<32;k4+=4){
      float4 v0 = vp[k4+0], v1 = vp[k4+1], v2 = vp[k4+2], v3 = vp[k4+3];
      a0 += wf[4*k4+0]*v0.x + wf[4*k4+1]*v0.y + wf[4*k4+2]*v0.z + wf[4*k4+3]*v0.w;
      a1 += wf[4*k4+4]*v1.x + wf[4*k4+5]*v1.y + wf[4*k4+6]*v1.z + wf[4*k4+7]*v1.w;
      a2 += wf[4*k4+8]*v2.x + wf[4*k4+9]*v2.y + wf[4*k4+10]*v2.z + wf[4*k4+11]*v2.w;
      a3 += wf[4*k4+12]*v3.x + wf[4*k4+13]*v3.y + wf[4*k4+14]*v3.z + wf[4*k4+15]*v3.w;
    }
    part[t] = (a0+a1)+(a2+a3);
    __syncthreads();
    if (t < 128){
      float hn = tanhf(part[t] + part[t+128] + bias);
      outws[(s0*UU + u)*HH + t] = hn;
      hbuf[t] = hn;
      if (s0 == SS-1) hlast[u*HH + t] = hn;
    }
    __syncthreads();
  }
}

// ---------------- preference projection ----------------
__global__ __launch_bounds__(256) void k_pproj(const int* __restrict__ au, const float* __restrict__ uemb,
    const float* __restrict__ projW, const float* __restrict__ projb, const float* __restrict__ pref,
    float* __restrict__ sp)
{
  int u = blockIdx.x, d = threadIdx.x;
  __shared__ float pl[128];
  int a = au[u];
  if (d < 128) pl[d] = uemb[(size_t)a*HH + d];
  __syncthreads();
  float acc = 0.f;
  #pragma unroll 4
  for(int k=0;k<128;k++) acc += pl[k]*projW[k*256 + d];
  sp[u*256 + d] = tanhf(acc + projb[d]) + pref[d];
}

__global__ __launch_bounds__(256) void k_xprojsim(const float* __restrict__ xemb,
   const float* __restrict__ projW, const float* __restrict__ projb,
   const float* __restrict__ sp, float* __restrict__ sim)
{
  int su = blockIdx.x; int s0 = su >> 7, u = su & 127;
  int d = threadIdx.x;
  __shared__ float xl[128];
  __shared__ float red[4];
  if (d < 128) xl[d] = xemb[su*HH + d];
  __syncthreads();
  float a0 = 0.f, a1 = 0.f;
  #pragma unroll 4
  for(int k=0;k<128;k+=2){
    a0 += xl[k]*projW[k*256 + d];
    a1 += xl[k+1]*projW[(k+1)*256 + d];
  }
  float xp = tanhf(a0 + a1 + projb[d]);
  float val = xp * sp[u*256 + d];
  for(int off=32; off>0; off>>=1) val += __shfl_down(val, off, 64);
  if ((d & 63) == 0) red[d>>6] = val;
  __syncthreads();
  if (d == 0){
    float sum = red[0]+red[1]+red[2]+red[3];
    sim[u*SS + s0] = 1.f/(1.f + expf(-sum));
  }
}

// ---------------- spatio-temporal decay + out_pu build (bf16 for GEMM A) ----------------
__global__ __launch_bounds__(256) void k_decay(const float* __restrict__ t_in, const float* __restrict__ s_in,
    const float* __restrict__ sim, const float* __restrict__ outws,
    const float* __restrict__ uemb, const int* __restrict__ au, u16* __restrict__ outpu)
{
  int u = blockIdx.x, tid = threadIdx.x;
  __shared__ float outL[SS*HH];
  __shared__ float wm[SS*SS];
  __shared__ float tl[SS], sx[SS], sy[SS], sml[SS], swv[SS];
  __shared__ u16 pub[HH];
  for(int idx=tid; idx<SS*HH; idx+=256){
    int j = idx >> 7, hh = idx & 127;
    outL[idx] = outws[(j*UU + u)*HH + hh];
  }
  if (tid < SS){
    tl[tid]  = t_in[tid*UU + u];
    sx[tid]  = s_in[(tid*UU + u)*2 + 0];
    sy[tid]  = s_in[(tid*UU + u)*2 + 1];
    sml[tid] = sim[u*SS + tid];
  }
  if (tid < HH) pub[tid] = f2b(uemb[(size_t)au[u]*HH + tid]);
  __syncthreads();
  for(int p=tid; p<SS*SS; p+=256){
    int i = p >> 5, j = p & 31;
    float wv = 0.f;
    if (j <= i){
      float dt = tl[i] - tl[j];
      float a = 0.5f*(cosf(dt * 7.2722052166430399e-05f) + 1.0f) * expf(dt * -1.1574074074074074e-06f);
      float dx = sx[i]-sx[j], dy = sy[i]-sy[j];
      float b = expf(-100.0f * sqrtf(dx*dx + dy*dy));
      wv = (a*b + 1e-10f) * sml[j];
    }
    wm[p] = wv;
  }
  __syncthreads();
  if (tid < SS){
    float ssum = 0.f;
    for(int j=0;j<=tid;j++) ssum += wm[tid*32 + j];
    swv[tid] = ssum;
  }
  __syncthreads();
  for(int p=tid; p<SS*HH; p+=256){
    int i = p >> 7, hh = p & 127;
    float accv = 0.f;
    for(int j=0;j<=i;j++) accv += wm[i*32 + j]*outL[j*128 + hh];
    size_t row = (size_t)(i*UU + u)*256;
    outpu[row + hh] = f2b(accv / swv[i]);
    outpu[row + 128 + hh] = pub[hh];
  }
}

// ---------------- transpose+cast fc_W [256,30000] f32 -> bf16 [30080,256] (zero-padded) ----------------
__global__ __launch_bounds__(256) void k_transp(const float* __restrict__ fcW, u16* __restrict__ fcwT){
  __shared__ u16 tl[64*65];
  int n0 = blockIdx.x*64, k0 = blockIdx.y*64;
  int tid = threadIdx.x;
  {
    int nn = tid & 63, k4 = tid >> 6;
    for (int r = 0; r < 16; ++r) {
      int kk = r*4 + k4;
      int n = n0 + nn;
      u16 v = 0;
      if (n < VV) v = f2b(fcW[(size_t)(k0+kk)*VV + n]);
      tl[kk*65 + nn] = v;
    }
  }
  __syncthreads();
  {
    int kk = tid & 63, n4 = tid >> 6;
    for (int r = 0; r < 16; ++r) {
      int nn = r*4 + n4;
      fcwT[(size_t)(n0+nn)*256 + k0 + kk] = tl[kk*65 + nn];
    }
  }
}

// ---------------- big GEMM: bf16 [4096,256] x [256,30000] + bias -> f32 ----------------
// v2: K-step 128 (2 iterations), XOR-swizzled staging (pre-swizzled global source,
// linear global_load_lds dest) -> conflict-free ds_read_b128; grid (m-fast, n-slow)
// so 32 consecutive blocks share the B tile in L2; LDS-free direct-store epilogue
// with nontemporal stores (C is write-once; keep L2 for B).
__global__ __launch_bounds__(256) void k_gemm(const u16* __restrict__ A, const u16* __restrict__ BT,
    const float* __restrict__ bias, float* __restrict__ C)
{
  __shared__ __align__(16) char As[32768];  // [128 m][256B = 128 k bf16], positions XOR-swizzled
  __shared__ __align__(16) char Bs[32768];  // [128 n][256B]
  const int tid  = threadIdx.x;
  const int lane = tid & 63;
  const int wv   = tid >> 6;          // wave 0..3
  const int wr = wv >> 1, wc = wv & 1;
  const int m0 = blockIdx.x * 128;    // x fastest: consecutive blocks share B tile
  const int n0 = blockIdx.y * 128;

  f32x4 acc[16];
  #pragma unroll
  for(int i=0;i<16;i++) acc[i] = (f32x4){0.f,0.f,0.f,0.f};

  const char* Ab = (const char*)A;    // row stride 512B (256 k * 2B)
  const char* Bb = (const char*)BT;
  // staging: load i in 0..7; LDS dest = i*4096 + tid*16 (linear, wave-uniform base + lane*16)
  //   -> LDS row = i*16 + (tid>>4), position p = tid&15
  // source supplies global chunk (p ^ (row&15)) so that reads with p' = p ^ fr are conflict-free
  const int srow = tid >> 4;                    // row&15 at stage time
  const int scol = ((tid & 15) ^ srow) << 4;    // swizzled byte offset within 256B k-chunk

  const int fr = lane & 15;
  const int kq = lane >> 4;           // 0..3

  for (int kt = 0; kt < 2; ++kt){
    __syncthreads();                  // kt=1: all waves done reading LDS
    #pragma unroll
    for (int i = 0; i < 8; ++i)
      gl_lds16(Ab + (size_t)(m0 + i*16 + srow)*512 + kt*256 + scol, As + i*4096 + wv*1024);
    #pragma unroll
    for (int i = 0; i < 8; ++i)
      gl_lds16(Bb + (size_t)(n0 + i*16 + srow)*512 + kt*256 + scol, Bs + i*4096 + wv*1024);
    __syncthreads();                  // drains vmcnt(0): staged data visible

    #pragma unroll
    for (int ks = 0; ks < 4; ++ks){
      bf16x8 af[4], bg[4];
      const int p = ((ks*4 + kq) ^ fr) << 4;   // swizzled read position (bytes)
      #pragma unroll
      for (int mt = 0; mt < 4; ++mt)
        af[mt] = *(const bf16x8*)(As + (wr*64 + mt*16 + fr)*256 + p);
      #pragma unroll
      for (int nt = 0; nt < 4; ++nt)
        bg[nt] = *(const bf16x8*)(Bs + (wc*64 + nt*16 + fr)*256 + p);
      #pragma unroll
      for (int mt = 0; mt < 4; ++mt)
        #pragma unroll
        for (int nt = 0; nt < 4; ++nt)
          acc[mt*4+nt] = __builtin_amdgcn_mfma_f32_16x16x32_bf16(af[mt], bg[nt], acc[mt*4+nt], 0, 0, 0);
    }
  }

  // epilogue: direct nontemporal stores, no LDS, no barriers
  const int n_base = n0 + wc*64;
  float bl[4];
  #pragma unroll
  for(int nt=0;nt<4;++nt){
    int n = n_base + nt*16 + fr;
    bl[nt] = (n < VV) ? bias[n] : 0.f;
  }
  const bool full = (n0 + 128 <= VV);          // block-uniform
  #pragma unroll
  for(int mt=0;mt<4;++mt){
    #pragma unroll
    for(int r=0;r<4;++r){
      size_t rowoff = (size_t)(m0 + wr*64 + mt*16 + kq*4 + r) * VV;
      if (full){
        #pragma unroll
        for(int nt=0;nt<4;++nt)
          __builtin_nontemporal_store(acc[mt*4+nt][r] + bl[nt], &C[rowoff + n_base + nt*16 + fr]);
      } else {
        #pragma unroll
        for(int nt=0;nt<4;++nt){
          int n = n_base + nt*16 + fr;
          if (n < VV) __builtin_nontemporal_store(acc[mt*4+nt][r] + bl[nt], &C[rowoff + n]);
        }
      }
    }
  }
}

extern "C" void kernel_launch(void* const* d_in, const int* in_sizes, int n_in,
                              void* d_out, int out_size, void* d_ws, size_t ws_size,
                              hipStream_t stream)
{
  (void)in_sizes; (void)n_in; (void)out_size; (void)ws_size;
  const int*   x      = (const int*)d_in[0];
  const float* t_in   = (const float*)d_in[1];
  const float* s_in   = (const float*)d_in[3];
  const float* h0     = (const float*)d_in[7];
  const int*   au     = (const int*)d_in[8];
  const int*   grows  = (const int*)d_in[9];
  const int*   gcols  = (const int*)d_in[10];
  const float* enc    = (const float*)d_in[11];
  const float* uemb   = (const float*)d_in[12];
  const float* pref   = (const float*)d_in[13];
  const float* projW  = (const float*)d_in[14];
  const float* projb  = (const float*)d_in[15];
  const float* Wih    = (const float*)d_in[16];
  const float* Whh    = (const float*)d_in[17];
  const float* brnn   = (const float*)d_in[18];
  const float* fcW    = (const float*)d_in[19];
  const float* fcb    = (const float*)d_in[20];
  float* yf = (float*)d_out;
  float* hlast = yf + (size_t)SS*UU*VV;
  char* ws = (char*)d_ws;
  // phase-1 region [0, 15,600,000): needed | deg | agg — dead after k_xemb,
  // then reused for fcwT (15,400,960 B) by k_transp.
  int*   needed = (int*)(ws + 0);
  int*   deg    = (int*)(ws + 120000);
  float* agg    = (float*)(ws + 240000);
  u16*   fcwT   = (u16*)(ws + 0);
  float* xemb   = (float*)(ws + 15600000);
  float* outws  = (float*)(ws + 17697152);
  float* sp     = (float*)(ws + 19794304);
  float* sim    = (float*)(ws + 19925376);
  u16*   outpu  = (u16*)(ws + 19941760);   // end 22,038,912 B

  hipMemsetAsync(ws, 0, 15600000, stream);  // needed + deg + agg
  hipLaunchKernelGGL(k_flagdeg,  dim3(1172),    dim3(256), 0, stream, x, grows, needed, deg);
  hipLaunchKernelGGL(k_agg,      dim3(2048),    dim3(256), 0, stream, grows, gcols, enc, needed, agg);
  hipLaunchKernelGGL(k_xemb,     dim3(SS*UU),   dim3(128), 0, stream, x, agg, enc, deg, xemb);
  hipLaunchKernelGGL(k_transp,   dim3(470,4),   dim3(256), 0, stream, fcW, fcwT);  // after xemb: overlays agg
  hipLaunchKernelGGL(k_rnn,      dim3(UU),      dim3(256), 0, stream, xemb, h0, Wih, Whh, brnn, outws, hlast);
  hipLaunchKernelGGL(k_pproj,    dim3(UU),      dim3(256), 0, stream, au, uemb, projW, projb, pref, sp);
  hipLaunchKernelGGL(k_xprojsim, dim3(SS*UU),   dim3(256), 0, stream, xemb, projW, projb, sp, sim);
  hipLaunchKernelGGL(k_decay,    dim3(UU),      dim3(256), 0, stream, t_in, s_in, sim, outws, uemb, au, outpu);
  hipLaunchKernelGGL(k_gemm,     dim3(32,235),  dim3(256), 0, stream, outpu, fcwT, fcb, yf);
}

// Round 2
// 764.604 us; speedup vs baseline: 1.1496x; 1.0135x over previous
//
#include <hip/hip_runtime.h>
#include <hip/hip_bf16.h>

#define VV 30000
#define HH 128
#define SS 32
#define UU 128
#define EE 300000

typedef unsigned short u16;
typedef unsigned int u32;

__device__ __forceinline__ u16 f2b(float f){ union{float f; u32 i;} v; v.f=f; u32 x=v.i; x += 0x7fffu + ((x>>16)&1u); return (u16)(x>>16); }

typedef __bf16 bf16x8 __attribute__((ext_vector_type(8)));
typedef float f32x4 __attribute__((ext_vector_type(4)));

__device__ __forceinline__ void gl_lds16(const void* g, void* l){
  __builtin_amdgcn_global_load_lds((const __attribute__((address_space(1))) u32*)g,
                                   (__attribute__((address_space(3))) u32*)l, 16, 0, 0);
}

// ---------------- graph conv ----------------
// merged flag (x -> needed) + degree (rows -> deg). grid = 1172 blocks covers EE.
__global__ __launch_bounds__(256) void k_flagdeg(const int* __restrict__ x, const int* __restrict__ rows,
    int* __restrict__ needed, int* __restrict__ deg){
  int gid = blockIdx.x*256 + threadIdx.x;
  if (gid < SS*UU) needed[x[gid]] = 1;
  if (gid < EE) atomicAdd(&deg[rows[gid]], 1);
}

// grid-stride over edges: 2048 blocks, 2 edges per block-iteration (128 threads/edge).
__global__ __launch_bounds__(256) void k_agg(const int* __restrict__ rows, const int* __restrict__ cols,
    const float* __restrict__ enc, const int* __restrict__ needed, float* __restrict__ agg){
  int hh  = threadIdx.x & 127;
  int sub = threadIdx.x >> 7;
  int stride = gridDim.x * 2;
  for (int e = blockIdx.x*2 + sub; e < EE; e += stride){
    int r = rows[e];                 // wave-uniform -> scalar load
    if (!needed[r]) continue;        // wave-uniform branch
    int c = cols[e];
    atomicAdd(&agg[(size_t)r*HH + hh], enc[(size_t)c*HH + hh]);
  }
}

__global__ __launch_bounds__(128) void k_xemb(const int* __restrict__ x, const float* __restrict__ agg,
    const float* __restrict__ enc, const int* __restrict__ deg, float* __restrict__ xemb){
  int su = blockIdx.x, hh = threadIdx.x;
  int v = x[su];
  float d = (float)(deg[v] + 1);
  xemb[su*HH + hh] = (agg[(size_t)v*HH + hh] + enc[(size_t)v*HH + hh]) / d;
}

// ---------------- RNN: one block per user, weights in registers ----------------
__global__ __launch_bounds__(256) void k_rnn(const float* __restrict__ xemb,
     const float* __restrict__ h0, const float* __restrict__ Wih, const float* __restrict__ Whh,
     const float* __restrict__ brnn, float* __restrict__ outws, float* __restrict__ hlast)
{
  int u = blockIdx.x, t = threadIdx.x;
  int d = t & 127, half = t >> 7;
  __shared__ float xbuf[128], hbuf[128], part[256];
  float wf[128];
  const float4* wr4 = (const float4*)((half ? Whh : Wih) + d*HH);
  #pragma unroll
  for(int i=0;i<32;i++){
    float4 q = wr4[i];
    wf[4*i+0]=q.x; wf[4*i+1]=q.y; wf[4*i+2]=q.z; wf[4*i+3]=q.w;
  }
  float bias = 0.f;
  if (t < 128){ hbuf[t] = h0[u*HH + t]; bias = brnn[t]; }
  for(int s0=0; s0<SS; ++s0){
    if (t < 128) xbuf[t] = xemb[(s0*UU + u)*HH + t];
    __syncthreads();
    const float4* vp = (const float4*)(half ? hbuf : xbuf);
    // 4 independent accumulators break the dependent-FMA chain
    float a0=0.f, a1=0.f, a2=0.f, a3=0.f;
    #pragma unroll
    for(int k4=0;k4<32;k4+=4){
      float4 v0 = vp[k4+0], v1 = vp[k4+1], v2 = vp[k4+2], v3 = vp[k4+3];
      a0 += wf[4*k4+0]*v0.x + wf[4*k4+1]*v0.y + wf[4*k4+2]*v0.z + wf[4*k4+3]*v0.w;
      a1 += wf[4*k4+4]*v1.x + wf[4*k4+5]*v1.y + wf[4*k4+6]*v1.z + wf[4*k4+7]*v1.w;
      a2 += wf[4*k4+8]*v2.x + wf[4*k4+9]*v2.y + wf[4*k4+10]*v2.z + wf[4*k4+11]*v2.w;
      a3 += wf[4*k4+12]*v3.x + wf[4*k4+13]*v3.y + wf[4*k4+14]*v3.z + wf[4*k4+15]*v3.w;
    }
    part[t] = (a0+a1)+(a2+a3);
    __syncthreads();
    if (t < 128){
      float hn = tanhf(part[t] + part[t+128] + bias);
      outws[(s0*UU + u)*HH + t] = hn;
      hbuf[t] = hn;
      if (s0 == SS-1) hlast[u*HH + t] = hn;
    }
    __syncthreads();
  }
}

// ---------------- fused preference projection + similarity ----------------
// grid = UU*8 blocks; block handles user u = bid>>3, s-batch s0 = (bid&7)*4.
// p_proj is recomputed per block (shares the projW load of the main k-loop);
// projW L2 traffic /4 vs per-(s,u) version; sp global round-trip eliminated.
__global__ __launch_bounds__(256) void k_prefsim(const int* __restrict__ au, const float* __restrict__ uemb,
    const float* __restrict__ projW, const float* __restrict__ projb, const float* __restrict__ pref,
    const float* __restrict__ xemb, float* __restrict__ sim)
{
  int bid = blockIdx.x;
  int u = bid >> 3, s0 = (bid & 7) * 4;
  int d = threadIdx.x;
  __shared__ float pl[128];
  __shared__ float xl[4*128];
  __shared__ float red2[4][4];
  int a = au[u];
  if (d < 128) pl[d] = uemb[(size_t)a*HH + d];
  for (int idx = d; idx < 4*128; idx += 256){
    int si = idx >> 7, k = idx & 127;
    xl[idx] = xemb[((size_t)(s0+si)*UU + u)*HH + k];
  }
  __syncthreads();
  float accp = 0.f;
  float acs0 = 0.f, acs1 = 0.f, acs2 = 0.f, acs3 = 0.f;
  #pragma unroll 4
  for (int k = 0; k < 128; ++k){
    float w = projW[k*256 + d];
    accp += pl[k]*w;
    acs0 += xl[0*128 + k]*w;
    acs1 += xl[1*128 + k]*w;
    acs2 += xl[2*128 + k]*w;
    acs3 += xl[3*128 + k]*w;
  }
  float pb = projb[d];
  float spd = tanhf(accp + pb) + pref[d];
  float acs[4] = {acs0, acs1, acs2, acs3};
  #pragma unroll
  for (int si = 0; si < 4; ++si){
    float val = tanhf(acs[si] + pb) * spd;
    for (int off = 32; off > 0; off >>= 1) val += __shfl_down(val, off, 64);
    if ((d & 63) == 0) red2[si][d >> 6] = val;
  }
  __syncthreads();
  if (d < 4){
    float sum = red2[d][0] + red2[d][1] + red2[d][2] + red2[d][3];
    sim[u*SS + s0 + d] = 1.f/(1.f + expf(-sum));
  }
}

// ---------------- spatio-temporal decay + out_pu build (bf16 for GEMM A) ----------------
__global__ __launch_bounds__(256) void k_decay(const float* __restrict__ t_in, const float* __restrict__ s_in,
    const float* __restrict__ sim, const float* __restrict__ outws,
    const float* __restrict__ uemb, const int* __restrict__ au, u16* __restrict__ outpu)
{
  int u = blockIdx.x, tid = threadIdx.x;
  __shared__ float outL[SS*HH];
  __shared__ float wm[SS*SS];
  __shared__ float tl[SS], sx[SS], sy[SS], sml[SS], swv[SS];
  __shared__ u16 pub[HH];
  for(int idx=tid; idx<SS*HH; idx+=256){
    int j = idx >> 7, hh = idx & 127;
    outL[idx] = outws[(j*UU + u)*HH + hh];
  }
  if (tid < SS){
    tl[tid]  = t_in[tid*UU + u];
    sx[tid]  = s_in[(tid*UU + u)*2 + 0];
    sy[tid]  = s_in[(tid*UU + u)*2 + 1];
    sml[tid] = sim[u*SS + tid];
  }
  if (tid < HH) pub[tid] = f2b(uemb[(size_t)au[u]*HH + tid]);
  __syncthreads();
  for(int p=tid; p<SS*SS; p+=256){
    int i = p >> 5, j = p & 31;
    float wv = 0.f;
    if (j <= i){
      float dt = tl[i] - tl[j];
      float a = 0.5f*(cosf(dt * 7.2722052166430399e-05f) + 1.0f) * expf(dt * -1.1574074074074074e-06f);
      float dx = sx[i]-sx[j], dy = sy[i]-sy[j];
      float b = expf(-100.0f * sqrtf(dx*dx + dy*dy));
      wv = (a*b + 1e-10f) * sml[j];
    }
    wm[p] = wv;
  }
  __syncthreads();
  if (tid < SS){
    float ssum = 0.f;
    for(int j=0;j<=tid;j++) ssum += wm[tid*32 + j];
    swv[tid] = ssum;
  }
  __syncthreads();
  for(int p=tid; p<SS*HH; p+=256){
    int i = p >> 7, hh = p & 127;
    float accv = 0.f;
    for(int j=0;j<=i;j++) accv += wm[i*32 + j]*outL[j*128 + hh];
    size_t row = (size_t)(i*UU + u)*256;
    outpu[row + hh] = f2b(accv / swv[i]);
    outpu[row + 128 + hh] = pub[hh];
  }
}

// ---------------- transpose+cast fc_W [256,30000] f32 -> bf16 [30080,256] (zero-padded) ----------------
__global__ __launch_bounds__(256) void k_transp(const float* __restrict__ fcW, u16* __restrict__ fcwT){
  __shared__ u16 tl[64*65];
  int n0 = blockIdx.x*64, k0 = blockIdx.y*64;
  int tid = threadIdx.x;
  {
    int nn = tid & 63, k4 = tid >> 6;
    for (int r = 0; r < 16; ++r) {
      int kk = r*4 + k4;
      int n = n0 + nn;
      u16 v = 0;
      if (n < VV) v = f2b(fcW[(size_t)(k0+kk)*VV + n]);
      tl[kk*65 + nn] = v;
    }
  }
  __syncthreads();
  {
    int kk = tid & 63, n4 = tid >> 6;
    for (int r = 0; r < 16; ++r) {
      int nn = r*4 + n4;
      fcwT[(size_t)(n0+nn)*256 + k0 + kk] = tl[kk*65 + nn];
    }
  }
}

// ---------------- big GEMM: bf16 [4096,256] x [256,30000] + bias -> f32 ----------------
// v3: XOR-swizzled conflict-free staging (pre-swizzled global source, linear
// global_load_lds dest); chunked-bijective XCD swizzle (7520 = 8*940) so each
// XCD owns a contiguous n-range -> B panels fetched ~once from HBM per chip
// instead of once per XCD; peeled K-loop (3 barriers not 4); LDS-free
// nontemporal direct-store epilogue.
__global__ __launch_bounds__(256, 2) void k_gemm(const u16* __restrict__ A, const u16* __restrict__ BT,
    const float* __restrict__ bias, float* __restrict__ C)
{
  __shared__ __align__(16) char As[32768];  // [128 m][256B = 128 k bf16], positions XOR-swizzled
  __shared__ __align__(16) char Bs[32768];  // [128 n][256B]
  const int tid  = threadIdx.x;
  const int lane = tid & 63;
  const int wv   = tid >> 6;          // wave 0..3
  const int wr = wv >> 1, wc = wv & 1;

  // chunked XCD swizzle: dispatch-linear id l -> work id w s.t. XCD (l&7)
  // processes a contiguous range of work; work is m-fastest within the range.
  const int l  = blockIdx.y * 32 + blockIdx.x;   // 0..7519, x fastest
  const int wk = (l & 7) * 940 + (l >> 3);       // 8 chunks x 940, bijective
  const int m0 = (wk & 31) * 128;
  const int n0 = (wk >> 5) * 128;

  f32x4 acc[16];
  #pragma unroll
  for(int i=0;i<16;i++) acc[i] = (f32x4){0.f,0.f,0.f,0.f};

  const char* Ab = (const char*)A;    // row stride 512B (256 k * 2B)
  const char* Bb = (const char*)BT;
  // staging: load i in 0..7; LDS dest = i*4096 + tid*16 (linear, wave-uniform base + lane*16)
  //   -> LDS row = i*16 + (tid>>4), position p = tid&15
  // source supplies global chunk (p ^ (row&15)) so that reads with p' = p ^ fr are conflict-free
  const int srow = tid >> 4;                    // row&15 at stage time
  const int scol = ((tid & 15) ^ srow) << 4;    // swizzled byte offset within 256B k-chunk

  const int fr = lane & 15;
  const int kq = lane >> 4;           // 0..3

  auto STAGE = [&](int kt){
    #pragma unroll
    for (int i = 0; i < 8; ++i)
      gl_lds16(Ab + (size_t)(m0 + i*16 + srow)*512 + kt*256 + scol, As + i*4096 + wv*1024);
    #pragma unroll
    for (int i = 0; i < 8; ++i)
      gl_lds16(Bb + (size_t)(n0 + i*16 + srow)*512 + kt*256 + scol, Bs + i*4096 + wv*1024);
  };
  auto COMPUTE = [&](){
    #pragma unroll
    for (int ks = 0; ks < 4; ++ks){
      bf16x8 af[4], bg[4];
      const int p = ((ks*4 + kq) ^ fr) << 4;   // swizzled read position (bytes)
      #pragma unroll
      for (int mt = 0; mt < 4; ++mt)
        af[mt] = *(const bf16x8*)(As + (wr*64 + mt*16 + fr)*256 + p);
      #pragma unroll
      for (int nt = 0; nt < 4; ++nt)
        bg[nt] = *(const bf16x8*)(Bs + (wc*64 + nt*16 + fr)*256 + p);
      #pragma unroll
      for (int mt = 0; mt < 4; ++mt)
        #pragma unroll
        for (int nt = 0; nt < 4; ++nt)
          acc[mt*4+nt] = __builtin_amdgcn_mfma_f32_16x16x32_bf16(af[mt], bg[nt], acc[mt*4+nt], 0, 0, 0);
    }
  };

  STAGE(0);
  __syncthreads();      // drains vmcnt(0): kt0 staged data visible
  COMPUTE();
  __syncthreads();      // all waves done reading kt0 LDS
  STAGE(1);
  __syncthreads();      // drains vmcnt(0): kt1 staged data visible
  COMPUTE();

  // epilogue: direct nontemporal stores, no LDS, no barriers
  const int n_base = n0 + wc*64;
  float bl[4];
  #pragma unroll
  for(int nt=0;nt<4;++nt){
    int n = n_base + nt*16 + fr;
    bl[nt] = (n < VV) ? bias[n] : 0.f;
  }
  const bool full = (n0 + 128 <= VV);          // block-uniform
  #pragma unroll
  for(int mt=0;mt<4;++mt){
    #pragma unroll
    for(int r=0;r<4;++r){
      size_t rowoff = (size_t)(m0 + wr*64 + mt*16 + kq*4 + r) * VV;
      if (full){
        #pragma unroll
        for(int nt=0;nt<4;++nt)
          __builtin_nontemporal_store(acc[mt*4+nt][r] + bl[nt], &C[rowoff + n_base + nt*16 + fr]);
      } else {
        #pragma unroll
        for(int nt=0;nt<4;++nt){
          int n = n_base + nt*16 + fr;
          if (n < VV) __builtin_nontemporal_store(acc[mt*4+nt][r] + bl[nt], &C[rowoff + n]);
        }
      }
    }
  }
}

extern "C" void kernel_launch(void* const* d_in, const int* in_sizes, int n_in,
                              void* d_out, int out_size, void* d_ws, size_t ws_size,
                              hipStream_t stream)
{
  (void)in_sizes; (void)n_in; (void)out_size; (void)ws_size;
  const int*   x      = (const int*)d_in[0];
  const float* t_in   = (const float*)d_in[1];
  const float* s_in   = (const float*)d_in[3];
  const float* h0     = (const float*)d_in[7];
  const int*   au     = (const int*)d_in[8];
  const int*   grows  = (const int*)d_in[9];
  const int*   gcols  = (const int*)d_in[10];
  const float* enc    = (const float*)d_in[11];
  const float* uemb   = (const float*)d_in[12];
  const float* pref   = (const float*)d_in[13];
  const float* projW  = (const float*)d_in[14];
  const float* projb  = (const float*)d_in[15];
  const float* Wih    = (const float*)d_in[16];
  const float* Whh    = (const float*)d_in[17];
  const float* brnn   = (const float*)d_in[18];
  const float* fcW    = (const float*)d_in[19];
  const float* fcb    = (const float*)d_in[20];
  float* yf = (float*)d_out;
  float* hlast = yf + (size_t)SS*UU*VV;
  char* ws = (char*)d_ws;
  // phase-1 region [0, 15,600,000): needed | deg | agg — dead after k_xemb,
  // then reused for fcwT (15,400,960 B) by k_transp.
  int*   needed = (int*)(ws + 0);
  int*   deg    = (int*)(ws + 120000);
  float* agg    = (float*)(ws + 240000);
  u16*   fcwT   = (u16*)(ws + 0);
  float* xemb   = (float*)(ws + 15600000);
  float* outws  = (float*)(ws + 17697152);
  float* sim    = (float*)(ws + 19925376);
  u16*   outpu  = (u16*)(ws + 19941760);   // end 22,038,912 B

  hipMemsetAsync(ws, 0, 15600000, stream);  // needed + deg + agg
  hipLaunchKernelGGL(k_flagdeg,  dim3(1172),    dim3(256), 0, stream, x, grows, needed, deg);
  hipLaunchKernelGGL(k_agg,      dim3(2048),    dim3(256), 0, stream, grows, gcols, enc, needed, agg);
  hipLaunchKernelGGL(k_xemb,     dim3(SS*UU),   dim3(128), 0, stream, x, agg, enc, deg, xemb);
  hipLaunchKernelGGL(k_transp,   dim3(470,4),   dim3(256), 0, stream, fcW, fcwT);  // after xemb: overlays agg
  hipLaunchKernelGGL(k_rnn,      dim3(UU),      dim3(256), 0, stream, xemb, h0, Wih, Whh, brnn, outws, hlast);
  hipLaunchKernelGGL(k_prefsim,  dim3(UU*8),    dim3(256), 0, stream, au, uemb, projW, projb, pref, xemb, sim);
  hipLaunchKernelGGL(k_decay,    dim3(UU),      dim3(256), 0, stream, t_in, s_in, sim, outws, uemb, au, outpu);
  hipLaunchKernelGGL(k_gemm,     dim3(32,235),  dim3(256), 0, stream, outpu, fcwT, fcb, yf);
}